// Round 14
// baseline (491.710 us; speedup 1.0000x reference)
//
#include <hip/hip_runtime.h>
#include <math.h>

constexpr int B  = 4;
constexpr int S  = 12;
constexpr int N  = 20000;
constexpr int HD = 64;
constexpr int E0 = 640000;
constexpr int EL = E0 + N;      // edges + self loops
constexpr int BN = B * N;
constexpr int CAP = 128;        // padded CSR bucket capacity (deg: mean 32, sd 5.7)

// ---------------- padded-bucket CSR build: one kernel, no scan ---------------
__global__ void scatter_kernel(const int* __restrict__ ei, int* __restrict__ cnt,
                               int* __restrict__ perm) {
    int e = blockIdx.x * blockDim.x + threadIdx.x;
    if (e >= EL) return;
    int s, d;
    if (e < E0) { s = ei[e]; d = ei[E0 + e]; }
    else        { s = e - E0; d = s; }
    int pos = atomicAdd(&cnt[d], 1) & (CAP - 1);   // mask: can't corrupt neighbors
    perm[d * CAP + pos] = s;
}

// ---- conv weight transpose: cwD[dt*4096 + c*64 + o] = cw[o*192 + c*3 + dt] --
__global__ void tw_kernel(const float* __restrict__ cw, float* __restrict__ cwD) {
    int i = blockIdx.x * blockDim.x + threadIdx.x;
    if (i >= HD * HD * 3) return;
    int o = i / (HD * 3), rem = i % (HD * 3), c = rem / 3, dt = rem % 3;
    cwD[dt * (HD * HD) + c * HD + o] = cw[i];
}

// ======== gemm_attn v4: conv-v7 shape — 1-wave blocks, rows via s_load ======
// Block = 64 threads = 1 wave, 16 nodes. Row address = base + j (uniform) ->
// scalar loads on the scalar pipe; wres[64] resident; no LDS, no barrier.
// Replaces v3's 256 ds_read_b128 broadcasts per wave.
template<int H>
__global__ __launch_bounds__(64, 2)
void gemm_attn_kernel(const float* __restrict__ hin, const float* __restrict__ w,
                      const float* __restrict__ asrc, const float* __restrict__ adst,
                      float* __restrict__ xe, float* __restrict__ es, float* __restrict__ ed) {
    int base = blockIdx.x * 16;         // BN = 5000*16 exact
    int lane = threadIdx.x;             // = k (output channel)
    float wres[HD];                     // w[c][lane] -> VGPRs, coalesced loads
    #pragma unroll
    for (int c = 0; c < HD; ++c) wres[c] = w[c * HD + lane];
    float as_ = asrc[lane], ad_ = adst[lane];
    #pragma unroll 1
    for (int j = 0; j < 16; ++j) {
        int t = base + j;
        const float* hp = hin + (size_t)t * HD;      // uniform -> s_load
        float a0 = 0.f, a1 = 0.f;                    // 2 chains for dep latency
        #pragma unroll
        for (int c = 0; c < HD; c += 2) {
            a0 = fmaf(hp[c],     wres[c],     a0);
            a1 = fmaf(hp[c + 1], wres[c + 1], a1);
        }
        float acc = a0 + a1;
        xe[(size_t)t * HD + lane] = acc;             // coalesced 256B store
        float t0 = acc * as_, t1 = acc * ad_;
        if (H == 8) {
            #pragma unroll
            for (int m = 1; m < 8; m <<= 1) {
                t0 += __shfl_xor(t0, m, 64);
                t1 += __shfl_xor(t1, m, 64);
            }
            if ((lane & 7) == 0) {
                es[t * 8 + (lane >> 3)] = t0;
                ed[t * 8 + (lane >> 3)] = t1;
            }
        } else {
            #pragma unroll
            for (int m = 1; m < 64; m <<= 1) {
                t0 += __shfl_xor(t0, m, 64);
                t1 += __shfl_xor(t1, m, 64);
            }
            if (lane == 0) { es[t] = t0; ed[t] = t1; }
        }
    }
}

// layer 0: proj fused in. h row computed per-lane, broadcast via LDS row write.
constexpr int GT = 64;                  // nodes per block (4 waves x 16)
__global__ __launch_bounds__(256, 4)
void fused0_kernel(const float* __restrict__ x, const float* __restrict__ pw,
                   const float* __restrict__ pb, const float* __restrict__ w,
                   const float* __restrict__ asrc, const float* __restrict__ adst,
                   float* __restrict__ xe, float* __restrict__ es, float* __restrict__ ed) {
    __shared__ float tile[GT * HD];
    __shared__ float xt[S * GT];
    int base = blockIdx.x * GT;
    for (int i = threadIdx.x; i < S * GT; i += 256) {
        int s = i >> 6, nl = i & 63;
        int t = base + nl, bb = t / N, n = t - bb * N;
        xt[i] = x[(bb * S + s) * N + n];          // coalesced per s-segment
    }
    int lane = threadIdx.x & 63;
    float wres[HD];
    #pragma unroll
    for (int c = 0; c < HD; ++c) wres[c] = w[c * HD + lane];
    float pwres[S];
    #pragma unroll
    for (int s = 0; s < S; ++s) pwres[s] = pw[s * HD + lane];
    float pbv = pb[lane];
    float as_ = asrc[lane], ad_ = adst[lane];
    __syncthreads();
    int wvid = threadIdx.x >> 6;
    // phase A: this wave's 16 h-rows (lane = channel), written to tile
    for (int j = wvid * 16; j < wvid * 16 + 16; ++j) {
        float hl = pbv;
        #pragma unroll
        for (int s = 0; s < S; ++s)
            hl = fmaf(xt[s * GT + j], pwres[s], hl);         // broadcast read
        tile[j * HD + lane] = hl;                            // own wave's row
    }
    // phase B: gemm + attn (reads only this wave's rows -> no barrier needed)
    for (int j = wvid * 16; j < wvid * 16 + 16; ++j) {
        int t = base + j;
        float acc = 0.f;
        #pragma unroll
        for (int cq = 0; cq < 16; ++cq) {
            float4 r = ((const float4*)tile)[j * 16 + cq];
            acc = fmaf(r.x, wres[4 * cq + 0], acc);
            acc = fmaf(r.y, wres[4 * cq + 1], acc);
            acc = fmaf(r.z, wres[4 * cq + 2], acc);
            acc = fmaf(r.w, wres[4 * cq + 3], acc);
        }
        xe[(size_t)t * HD + lane] = acc;
        float t0 = acc * as_, t1 = acc * ad_;
        #pragma unroll
        for (int m = 1; m < 8; m <<= 1) {
            t0 += __shfl_xor(t0, m, 64);
            t1 += __shfl_xor(t1, m, 64);
        }
        if ((lane & 7) == 0) {
            es[t * 8 + (lane >> 3)] = t0;
            ed[t * 8 + (lane >> 3)] = t1;
        }
    }
}

// ------- fused aggregation, channel-half split for L2 residency --------------
// Grid 40000: g&7 = XCD id = bb*2+hf (round-robin CP heuristic). Each
// (batch,half) gathers 128B/edge from a 2.55MB xe half-slice -> fits ONE
// XCD's 4MB L2. Wave = 8 groups x 8 lanes: group owns an edge, lane owns
// 4 channels of the 32-channel half; p/exp recomputed per half (cheap).
template<int H, bool DO_ELU>
__global__ __launch_bounds__(256, 8)
void agg_kernel(const float* __restrict__ xe, const float* __restrict__ es,
                const float* __restrict__ ed, const int* __restrict__ cnt,
                const int* __restrict__ perm, const float* __restrict__ bias,
                float* __restrict__ hout) {
    int g = blockIdx.x;                       // 40000 blocks
    int bb  = (g & 7) >> 1;                   // batch
    int hf  = g & 1;                          // channel half
    int idx = g >> 3;                         // 0..4999
    int node = idx * 4 + (threadIdx.x >> 6);  // < 20000
    int lane  = threadIdx.x & 63;
    int group = lane >> 3;                    // 8 groups of 8 lanes
    int c4    = lane & 7;                     // float4 index within half
    int deg = cnt[node];
    int baseE = node * CAP;
    int h = (H == 8) ? (hf * 4 + (c4 >> 1)) : 0;  // head of channels hf*32+c4*4..+3
    const float*  es_b = es + bb * (N * H);
    const float4* xe4  = (const float4*)(xe + bb * (N * HD));
    float edv = ed[(bb * N + node) * H + h];
    float4 acc = {0.f, 0.f, 0.f, 0.f};
    float ssum = 0.f;
    #pragma unroll 4
    for (int jb = 0; jb < deg; jb += 8) {
        int j = jb + group;
        bool valid = (j < deg);
        int src = perm[baseE + (valid ? j : 0)];     // slot 0 always exists
        float e = es_b[src * H + h] + edv;
        e = fmaxf(e, 0.2f * e);                      // leaky_relu(0.2)
        float p = valid ? __expf(e) : 0.f;
        ssum += p;
        float4 xv = xe4[src * 16 + hf * 8 + c4];     // 128B/group gather
        acc.x = fmaf(p, xv.x, acc.x);
        acc.y = fmaf(p, xv.y, acc.y);
        acc.z = fmaf(p, xv.z, acc.z);
        acc.w = fmaf(p, xv.w, acc.w);
    }
    #pragma unroll
    for (int m = 8; m < 64; m <<= 1) {               // reduce across 8 groups
        acc.x += __shfl_xor(acc.x, m, 64);
        acc.y += __shfl_xor(acc.y, m, 64);
        acc.z += __shfl_xor(acc.z, m, 64);
        acc.w += __shfl_xor(acc.w, m, 64);
        ssum  += __shfl_xor(ssum,  m, 64);
    }
    if (lane < 8) {
        float inv = 1.f / ssum;
        float4 bv = ((const float4*)bias)[hf * 8 + lane];
        float4 r;
        r.x = acc.x * inv + bv.x;
        r.y = acc.y * inv + bv.y;
        r.z = acc.z * inv + bv.z;
        r.w = acc.w * inv + bv.w;
        if (DO_ELU) {
            r.x = (r.x > 0.f) ? r.x : expm1f(r.x);
            r.y = (r.y > 0.f) ? r.y : expm1f(r.y);
            r.z = (r.z > 0.f) ? r.z : expm1f(r.z);
            r.w = (r.w > 0.f) ? r.w : expm1f(r.w);
        }
        ((float4*)hout)[(bb * N + node) * 16 + hf * 8 + lane] = r;
    }
}

// ======== conv v7: 1-wave blocks, node rows via SCALAR loads (R13, 69us) =====
constexpr int CVN = 16;                 // nodes per (1-wave) block
__global__ __launch_bounds__(64, 2)
void conv_out_kernel(const float* __restrict__ h, const float* __restrict__ cwD,
                     const float* __restrict__ cb, const float* __restrict__ ow,
                     const float* __restrict__ ob, float* __restrict__ out) {
    __shared__ float part[CVN * HD];    // 4KB, wave-private
    int bb = blockIdx.y;
    int base = blockIdx.x * CVN;        // N = 1250*16 exact
    int lane = threadIdx.x;             // = output channel o
    float cbv = cb[lane];
    float ow0 = ow[lane * 3 + 0], ow1 = ow[lane * 3 + 1], ow2 = ow[lane * 3 + 2];
    float ob0 = ob[0], ob1 = ob[1], ob2 = ob[2];
    #pragma unroll
    for (int j = 0; j < CVN; ++j) part[j * HD + lane] = cbv;
    #pragma unroll 1
    for (int dt = 0; dt < 3; ++dt) {
        float wres[HD];                 // cwD[dt][c][lane], coalesced VMEM
        #pragma unroll
        for (int c = 0; c < HD; ++c) wres[c] = cwD[dt * (HD * HD) + c * HD + lane];
        #pragma unroll 1
        for (int j = 0; j < CVN; ++j) {
            int m = base + j + dt - 1;
            if (m >= 0 && m < N) {      // uniform branch (s_cbranch)
                const float* hp = h + ((size_t)bb * N + m) * HD;   // uniform -> s_load
                float a = 0.f;
                #pragma unroll
                for (int c = 0; c < HD; ++c)
                    a = fmaf(hp[c], wres[c], a);    // v_fma with SGPR operand
                part[j * HD + lane] += a;           // wave-local LDS RMW
            }
        }
    }
    // epilogue: relu + 64->3 via butterfly
    #pragma unroll 1
    for (int j = 0; j < CVN; ++j) {
        float v = fmaxf(part[j * HD + lane], 0.f);
        float t0 = v * ow0, t1 = v * ow1, t2 = v * ow2;
        #pragma unroll
        for (int m = 1; m < 64; m <<= 1) {
            t0 += __shfl_xor(t0, m, 64);
            t1 += __shfl_xor(t1, m, 64);
            t2 += __shfl_xor(t2, m, 64);
        }
        int n = base + j;               // always < N (1250*16 = 20000)
        if (lane < 3) {
            float r = (lane == 0) ? t0 + ob0 : (lane == 1) ? t1 + ob1 : t2 + ob2;
            out[(size_t)bb * 3 * N + lane * N + n] = r;
        }
    }
}

extern "C" void kernel_launch(void* const* d_in, const int* in_sizes, int n_in,
                              void* d_out, int out_size, void* d_ws, size_t ws_size,
                              hipStream_t stream) {
    const float* x      = (const float*)d_in[0];
    const int*   ei     = (const int*)  d_in[1];
    const float* proj_w = (const float*)d_in[2];
    const float* proj_b = (const float*)d_in[3];
    const float* g_w [3] = {(const float*)d_in[4], (const float*)d_in[8],  (const float*)d_in[12]};
    const float* g_as[3] = {(const float*)d_in[5], (const float*)d_in[9],  (const float*)d_in[13]};
    const float* g_ad[3] = {(const float*)d_in[6], (const float*)d_in[10], (const float*)d_in[14]};
    const float* g_b [3] = {(const float*)d_in[7], (const float*)d_in[11], (const float*)d_in[15]};
    const float* conv_w = (const float*)d_in[16];
    const float* conv_b = (const float*)d_in[17];
    const float* out_w  = (const float*)d_in[18];
    const float* out_b  = (const float*)d_in[19];
    float* out = (float*)d_out;

    // workspace layout (fp32 elements)
    float* bufA = (float*)d_ws;                      // BN*HD
    float* bufX = bufA + (size_t)BN * HD;            // BN*HD
    float* es   = bufX + (size_t)BN * HD;            // BN*8 (max H)
    float* ed   = es   + (size_t)BN * 8;             // BN*8
    int* cnt  = (int*)(ed + (size_t)BN * 8);         // N
    int* perm = cnt + N;                             // N*CAP
    float* cwD = (float*)(perm + (size_t)N * CAP);   // 3*64*64

    const int TB = 256;
    const int gE = (EL + TB - 1) / TB;

    // CSR build: memset + single scatter (padded buckets, no scan)
    hipMemsetAsync(cnt, 0, N * sizeof(int), stream);
    scatter_kernel<<<gE, TB, 0, stream>>>(ei, cnt, perm);

    // conv weight transpose to [dt][c][o]
    tw_kernel<<<(HD * HD * 3 + TB - 1) / TB, TB, 0, stream>>>(conv_w, cwD);

    // layer 0: proj + gemm + attn fused (reads x directly)
    fused0_kernel<<<BN / GT, TB, 0, stream>>>(x, proj_w, proj_b, g_w[0], g_as[0], g_ad[0],
                                              bufX, es, ed);
    agg_kernel<8, true><<<(BN / 4) * 2, TB, 0, stream>>>(bufX, es, ed, cnt, perm, g_b[0], bufA);

    // layer 1 (H=8) + ELU
    gemm_attn_kernel<8><<<BN / 16, 64, 0, stream>>>(bufA, g_w[1], g_as[1], g_ad[1], bufX, es, ed);
    agg_kernel<8, true><<<(BN / 4) * 2, TB, 0, stream>>>(bufX, es, ed, cnt, perm, g_b[1], bufA);

    // layer 2 (H=1), no ELU
    gemm_attn_kernel<1><<<BN / 16, 64, 0, stream>>>(bufA, g_w[2], g_as[2], g_ad[2], bufX, es, ed);
    agg_kernel<1, false><<<(BN / 4) * 2, TB, 0, stream>>>(bufX, es, ed, cnt, perm, g_b[2], bufA);

    // conv1d(k=3) + relu + final projection, writes [B,3,N]
    conv_out_kernel<<<dim3(N / CVN, B), 64, 0, stream>>>(bufA, cwD, conv_b, out_w, out_b, out);
}

// Round 15
// 462.882 us; speedup vs baseline: 1.0623x; 1.0623x over previous
//
#include <hip/hip_runtime.h>
#include <math.h>

constexpr int B  = 4;
constexpr int S  = 12;
constexpr int N  = 20000;
constexpr int HD = 64;
constexpr int E0 = 640000;
constexpr int EL = E0 + N;      // edges + self loops
constexpr int BN = B * N;
constexpr int CAP = 128;        // padded CSR bucket capacity (deg: mean 32, sd 5.7)

// ---------------- padded-bucket CSR build: one kernel, no scan ---------------
__global__ void scatter_kernel(const int* __restrict__ ei, int* __restrict__ cnt,
                               int* __restrict__ perm) {
    int e = blockIdx.x * blockDim.x + threadIdx.x;
    if (e >= EL) return;
    int s, d;
    if (e < E0) { s = ei[e]; d = ei[E0 + e]; }
    else        { s = e - E0; d = s; }
    int pos = atomicAdd(&cnt[d], 1) & (CAP - 1);   // mask: can't corrupt neighbors
    perm[d * CAP + pos] = s;
}

// ---- conv weight transpose: cwD[dt*4096 + c*64 + o] = cw[o*192 + c*3 + dt] --
__global__ void tw_kernel(const float* __restrict__ cw, float* __restrict__ cwD) {
    int i = blockIdx.x * blockDim.x + threadIdx.x;
    if (i >= HD * HD * 3) return;
    int o = i / (HD * 3), rem = i % (HD * 3), c = rem / 3, dt = rem % 3;
    cwD[dt * (HD * HD) + c * HD + o] = cw[i];
}

// ======== gemm_attn v4: 1-wave blocks, rows via s_load (kept from R14) ======
template<int H>
__global__ __launch_bounds__(64, 2)
void gemm_attn_kernel(const float* __restrict__ hin, const float* __restrict__ w,
                      const float* __restrict__ asrc, const float* __restrict__ adst,
                      float* __restrict__ xe, float* __restrict__ es, float* __restrict__ ed) {
    int base = blockIdx.x * 16;         // BN = 5000*16 exact
    int lane = threadIdx.x;             // = k (output channel)
    float wres[HD];                     // w[c][lane] -> VGPRs, coalesced loads
    #pragma unroll
    for (int c = 0; c < HD; ++c) wres[c] = w[c * HD + lane];
    float as_ = asrc[lane], ad_ = adst[lane];
    #pragma unroll 1
    for (int j = 0; j < 16; ++j) {
        int t = base + j;
        const float* hp = hin + (size_t)t * HD;      // uniform -> s_load
        float a0 = 0.f, a1 = 0.f;                    // 2 chains for dep latency
        #pragma unroll
        for (int c = 0; c < HD; c += 2) {
            a0 = fmaf(hp[c],     wres[c],     a0);
            a1 = fmaf(hp[c + 1], wres[c + 1], a1);
        }
        float acc = a0 + a1;
        xe[(size_t)t * HD + lane] = acc;             // coalesced 256B store
        float t0 = acc * as_, t1 = acc * ad_;
        if (H == 8) {
            #pragma unroll
            for (int m = 1; m < 8; m <<= 1) {
                t0 += __shfl_xor(t0, m, 64);
                t1 += __shfl_xor(t1, m, 64);
            }
            if ((lane & 7) == 0) {
                es[t * 8 + (lane >> 3)] = t0;
                ed[t * 8 + (lane >> 3)] = t1;
            }
        } else {
            #pragma unroll
            for (int m = 1; m < 64; m <<= 1) {
                t0 += __shfl_xor(t0, m, 64);
                t1 += __shfl_xor(t1, m, 64);
            }
            if (lane == 0) { es[t] = t0; ed[t] = t1; }
        }
    }
}

// layer 0: proj fused in. h row computed per-lane, broadcast via LDS row write.
constexpr int GT = 64;                  // nodes per block (4 waves x 16)
__global__ __launch_bounds__(256, 4)
void fused0_kernel(const float* __restrict__ x, const float* __restrict__ pw,
                   const float* __restrict__ pb, const float* __restrict__ w,
                   const float* __restrict__ asrc, const float* __restrict__ adst,
                   float* __restrict__ xe, float* __restrict__ es, float* __restrict__ ed) {
    __shared__ float tile[GT * HD];
    __shared__ float xt[S * GT];
    int base = blockIdx.x * GT;
    for (int i = threadIdx.x; i < S * GT; i += 256) {
        int s = i >> 6, nl = i & 63;
        int t = base + nl, bb = t / N, n = t - bb * N;
        xt[i] = x[(bb * S + s) * N + n];          // coalesced per s-segment
    }
    int lane = threadIdx.x & 63;
    float wres[HD];
    #pragma unroll
    for (int c = 0; c < HD; ++c) wres[c] = w[c * HD + lane];
    float pwres[S];
    #pragma unroll
    for (int s = 0; s < S; ++s) pwres[s] = pw[s * HD + lane];
    float pbv = pb[lane];
    float as_ = asrc[lane], ad_ = adst[lane];
    __syncthreads();
    int wvid = threadIdx.x >> 6;
    // phase A: this wave's 16 h-rows (lane = channel), written to tile
    for (int j = wvid * 16; j < wvid * 16 + 16; ++j) {
        float hl = pbv;
        #pragma unroll
        for (int s = 0; s < S; ++s)
            hl = fmaf(xt[s * GT + j], pwres[s], hl);         // broadcast read
        tile[j * HD + lane] = hl;                            // own wave's row
    }
    // phase B: gemm + attn (reads only this wave's rows -> no barrier needed)
    for (int j = wvid * 16; j < wvid * 16 + 16; ++j) {
        int t = base + j;
        float acc = 0.f;
        #pragma unroll
        for (int cq = 0; cq < 16; ++cq) {
            float4 r = ((const float4*)tile)[j * 16 + cq];
            acc = fmaf(r.x, wres[4 * cq + 0], acc);
            acc = fmaf(r.y, wres[4 * cq + 1], acc);
            acc = fmaf(r.z, wres[4 * cq + 2], acc);
            acc = fmaf(r.w, wres[4 * cq + 3], acc);
        }
        xe[(size_t)t * HD + lane] = acc;
        float t0 = acc * as_, t1 = acc * ad_;
        #pragma unroll
        for (int m = 1; m < 8; m <<= 1) {
            t0 += __shfl_xor(t0, m, 64);
            t1 += __shfl_xor(t1, m, 64);
        }
        if ((lane & 7) == 0) {
            es[t * 8 + (lane >> 3)] = t0;
            ed[t * 8 + (lane >> 3)] = t1;
        }
    }
}

// ------- fused aggregation (R13 proven form): one wave per (batch,node) ------
// 4 groups x 16 lanes; group owns an edge, lane owns 4 channels (float4).
// Full 64-channel rows: ~4 VALU/edge (near the structural floor). R14's
// channel-half split halved FETCH but doubled VALU (100% busy) -> reverted.
template<int H, bool DO_ELU>
__global__ __launch_bounds__(256, 8)
void agg_kernel(const float* __restrict__ xe, const float* __restrict__ es,
                const float* __restrict__ ed, const int* __restrict__ cnt,
                const int* __restrict__ perm, const float* __restrict__ bias,
                float* __restrict__ hout) {
    int g = blockIdx.x;                       // 20000 blocks, multiple of 8
    int bb   = (g & 7) >> 1;                  // batch from XCD pair
    int idx  = (g >> 3) * 2 + (g & 1);        // 0..4999 within batch
    int node = idx * 4 + (threadIdx.x >> 6);  // < 20000
    int lane  = threadIdx.x & 63;
    int group = lane >> 4;
    int c4    = lane & 15;
    int deg = cnt[node];
    int baseE = node * CAP;
    int h = (H == 8) ? (c4 >> 1) : 0;        // channels 4*c4..+3 lie in one head
    const float*  es_b = es + bb * (N * H);
    const float4* xe4  = (const float4*)(xe + bb * (N * HD));
    float edv = ed[(bb * N + node) * H + h];
    float4 acc = {0.f, 0.f, 0.f, 0.f};
    float ssum = 0.f;
    #pragma unroll 4
    for (int jb = 0; jb < deg; jb += 4) {
        int j = jb + group;
        bool valid = (j < deg);
        int src = perm[baseE + (valid ? j : 0)];     // slot 0 always exists
        float e = es_b[src * H + h] + edv;
        e = fmaxf(e, 0.2f * e);                      // leaky_relu(0.2)
        float p = valid ? __expf(e) : 0.f;
        ssum += p;
        float4 xv = xe4[src * 16 + c4];              // 256B/group gather
        acc.x = fmaf(p, xv.x, acc.x);
        acc.y = fmaf(p, xv.y, acc.y);
        acc.z = fmaf(p, xv.z, acc.z);
        acc.w = fmaf(p, xv.w, acc.w);
    }
    #pragma unroll
    for (int m = 16; m < 64; m <<= 1) {
        acc.x += __shfl_xor(acc.x, m, 64);
        acc.y += __shfl_xor(acc.y, m, 64);
        acc.z += __shfl_xor(acc.z, m, 64);
        acc.w += __shfl_xor(acc.w, m, 64);
        ssum  += __shfl_xor(ssum,  m, 64);
    }
    if (lane < 16) {
        float inv = 1.f / ssum;
        const float4* b4 = (const float4*)bias;
        float4 bv = b4[c4];
        float4 r;
        r.x = acc.x * inv + bv.x;
        r.y = acc.y * inv + bv.y;
        r.z = acc.z * inv + bv.z;
        r.w = acc.w * inv + bv.w;
        if (DO_ELU) {
            r.x = (r.x > 0.f) ? r.x : expm1f(r.x);
            r.y = (r.y > 0.f) ? r.y : expm1f(r.y);
            r.z = (r.z > 0.f) ? r.z : expm1f(r.z);
            r.w = (r.w > 0.f) ? r.w : expm1f(r.w);
        }
        ((float4*)hout)[(bb * N + node) * 16 + c4] = r;
    }
}

// ======== conv v7.1: 1-wave blocks, rows via s_load; j-loop unroll 2 ========
// Unroll 2 keeps two rows' scalar loads in flight to cover s_load latency
// (the measured gap: VALU content ~14us vs 69us dur at VALUBusy 42%).
constexpr int CVN = 16;                 // nodes per (1-wave) block
__global__ __launch_bounds__(64, 2)
void conv_out_kernel(const float* __restrict__ h, const float* __restrict__ cwD,
                     const float* __restrict__ cb, const float* __restrict__ ow,
                     const float* __restrict__ ob, float* __restrict__ out) {
    __shared__ float part[CVN * HD];    // 4KB, wave-private
    int bb = blockIdx.y;
    int base = blockIdx.x * CVN;        // N = 1250*16 exact
    int lane = threadIdx.x;             // = output channel o
    float cbv = cb[lane];
    float ow0 = ow[lane * 3 + 0], ow1 = ow[lane * 3 + 1], ow2 = ow[lane * 3 + 2];
    float ob0 = ob[0], ob1 = ob[1], ob2 = ob[2];
    #pragma unroll
    for (int j = 0; j < CVN; ++j) part[j * HD + lane] = cbv;
    #pragma unroll 1
    for (int dt = 0; dt < 3; ++dt) {
        float wres[HD];                 // cwD[dt][c][lane], coalesced VMEM
        #pragma unroll
        for (int c = 0; c < HD; ++c) wres[c] = cwD[dt * (HD * HD) + c * HD + lane];
        #pragma unroll 2
        for (int j = 0; j < CVN; ++j) {
            int m = base + j + dt - 1;
            if (m >= 0 && m < N) {      // uniform branch (s_cbranch)
                const float* hp = h + ((size_t)bb * N + m) * HD;   // uniform -> s_load
                float a = 0.f;
                #pragma unroll
                for (int c = 0; c < HD; ++c)
                    a = fmaf(hp[c], wres[c], a);    // v_fma with SGPR operand
                part[j * HD + lane] += a;           // wave-local LDS RMW
            }
        }
    }
    // epilogue: relu + 64->3 via butterfly
    #pragma unroll 1
    for (int j = 0; j < CVN; ++j) {
        float v = fmaxf(part[j * HD + lane], 0.f);
        float t0 = v * ow0, t1 = v * ow1, t2 = v * ow2;
        #pragma unroll
        for (int m = 1; m < 64; m <<= 1) {
            t0 += __shfl_xor(t0, m, 64);
            t1 += __shfl_xor(t1, m, 64);
            t2 += __shfl_xor(t2, m, 64);
        }
        int n = base + j;               // always < N (1250*16 = 20000)
        if (lane < 3) {
            float r = (lane == 0) ? t0 + ob0 : (lane == 1) ? t1 + ob1 : t2 + ob2;
            out[(size_t)bb * 3 * N + lane * N + n] = r;
        }
    }
}

extern "C" void kernel_launch(void* const* d_in, const int* in_sizes, int n_in,
                              void* d_out, int out_size, void* d_ws, size_t ws_size,
                              hipStream_t stream) {
    const float* x      = (const float*)d_in[0];
    const int*   ei     = (const int*)  d_in[1];
    const float* proj_w = (const float*)d_in[2];
    const float* proj_b = (const float*)d_in[3];
    const float* g_w [3] = {(const float*)d_in[4], (const float*)d_in[8],  (const float*)d_in[12]};
    const float* g_as[3] = {(const float*)d_in[5], (const float*)d_in[9],  (const float*)d_in[13]};
    const float* g_ad[3] = {(const float*)d_in[6], (const float*)d_in[10], (const float*)d_in[14]};
    const float* g_b [3] = {(const float*)d_in[7], (const float*)d_in[11], (const float*)d_in[15]};
    const float* conv_w = (const float*)d_in[16];
    const float* conv_b = (const float*)d_in[17];
    const float* out_w  = (const float*)d_in[18];
    const float* out_b  = (const float*)d_in[19];
    float* out = (float*)d_out;

    // workspace layout (fp32 elements)
    float* bufA = (float*)d_ws;                      // BN*HD
    float* bufX = bufA + (size_t)BN * HD;            // BN*HD
    float* es   = bufX + (size_t)BN * HD;            // BN*8 (max H)
    float* ed   = es   + (size_t)BN * 8;             // BN*8
    int* cnt  = (int*)(ed + (size_t)BN * 8);         // N
    int* perm = cnt + N;                             // N*CAP
    float* cwD = (float*)(perm + (size_t)N * CAP);   // 3*64*64

    const int TB = 256;
    const int gE = (EL + TB - 1) / TB;

    // CSR build: memset + single scatter (padded buckets, no scan)
    hipMemsetAsync(cnt, 0, N * sizeof(int), stream);
    scatter_kernel<<<gE, TB, 0, stream>>>(ei, cnt, perm);

    // conv weight transpose to [dt][c][o]
    tw_kernel<<<(HD * HD * 3 + TB - 1) / TB, TB, 0, stream>>>(conv_w, cwD);

    // layer 0: proj + gemm + attn fused (reads x directly)
    fused0_kernel<<<BN / GT, TB, 0, stream>>>(x, proj_w, proj_b, g_w[0], g_as[0], g_ad[0],
                                              bufX, es, ed);
    agg_kernel<8, true><<<BN / 4, TB, 0, stream>>>(bufX, es, ed, cnt, perm, g_b[0], bufA);

    // layer 1 (H=8) + ELU
    gemm_attn_kernel<8><<<BN / 16, 64, 0, stream>>>(bufA, g_w[1], g_as[1], g_ad[1], bufX, es, ed);
    agg_kernel<8, true><<<BN / 4, TB, 0, stream>>>(bufX, es, ed, cnt, perm, g_b[1], bufA);

    // layer 2 (H=1), no ELU
    gemm_attn_kernel<1><<<BN / 16, 64, 0, stream>>>(bufA, g_w[2], g_as[2], g_ad[2], bufX, es, ed);
    agg_kernel<1, false><<<BN / 4, TB, 0, stream>>>(bufX, es, ed, cnt, perm, g_b[2], bufA);

    // conv1d(k=3) + relu + final projection, writes [B,3,N]
    conv_out_kernel<<<dim3(N / CVN, B), 64, 0, stream>>>(bufA, cwD, conv_b, out_w, out_b, out);
}

// Round 16
// 444.550 us; speedup vs baseline: 1.1061x; 1.0412x over previous
//
#include <hip/hip_runtime.h>
#include <math.h>

constexpr int B  = 4;
constexpr int S  = 12;
constexpr int N  = 20000;
constexpr int HD = 64;
constexpr int E0 = 640000;
constexpr int EL = E0 + N;      // edges + self loops
constexpr int BN = B * N;
constexpr int CAP = 128;        // padded CSR bucket capacity (deg: mean 32, sd 5.7)

// ---------------- padded-bucket CSR build: one kernel, no scan ---------------
__global__ void scatter_kernel(const int* __restrict__ ei, int* __restrict__ cnt,
                               int* __restrict__ perm) {
    int e = blockIdx.x * blockDim.x + threadIdx.x;
    if (e >= EL) return;
    int s, d;
    if (e < E0) { s = ei[e]; d = ei[E0 + e]; }
    else        { s = e - E0; d = s; }
    int pos = atomicAdd(&cnt[d], 1) & (CAP - 1);   // mask: can't corrupt neighbors
    perm[d * CAP + pos] = s;
}

// ---- conv weight transpose: cwD[dt*4096 + c*64 + o] = cw[o*192 + c*3 + dt] --
__global__ void tw_kernel(const float* __restrict__ cw, float* __restrict__ cwD) {
    int i = blockIdx.x * blockDim.x + threadIdx.x;
    if (i >= HD * HD * 3) return;
    int o = i / (HD * 3), rem = i % (HD * 3), c = rem / 3, dt = rem % 3;
    cwD[dt * (HD * HD) + c * HD + o] = cw[i];
}

// ======== gemm family v3 (R13-proven): lane = k, weights resident in VGPRs ==
// wave processes 16 nodes; node rows broadcast from LDS (wave-uniform addr);
// xe stored directly (coalesced 256B per node); es/ed via butterfly shuffle.
// (v4 1-wave s_load variant measured +9us/dispatch worse — R15.)
constexpr int GT = 64;                  // nodes per block (4 waves x 16)

template<int H>
__global__ __launch_bounds__(256, 4)
void gemm_attn_kernel(const float* __restrict__ hin, const float* __restrict__ w,
                      const float* __restrict__ asrc, const float* __restrict__ adst,
                      float* __restrict__ xe, float* __restrict__ es, float* __restrict__ ed) {
    __shared__ float tile[GT * HD];
    int base = blockIdx.x * GT;
    for (int i = threadIdx.x; i < GT * (HD / 4); i += 256)
        ((float4*)tile)[i] = ((const float4*)(hin + (size_t)base * HD))[i];
    int lane = threadIdx.x & 63;
    float wres[HD];                     // w[c][lane], c compile-time -> VGPRs
    #pragma unroll
    for (int c = 0; c < HD; ++c) wres[c] = w[c * HD + lane];
    float as_ = asrc[lane], ad_ = adst[lane];
    __syncthreads();
    int wvid = threadIdx.x >> 6;
    for (int j = wvid * 16; j < wvid * 16 + 16; ++j) {
        int t = base + j;
        float acc = 0.f;
        #pragma unroll
        for (int cq = 0; cq < 16; ++cq) {
            float4 r = ((const float4*)tile)[j * 16 + cq];   // broadcast read
            acc = fmaf(r.x, wres[4 * cq + 0], acc);
            acc = fmaf(r.y, wres[4 * cq + 1], acc);
            acc = fmaf(r.z, wres[4 * cq + 2], acc);
            acc = fmaf(r.w, wres[4 * cq + 3], acc);
        }
        xe[(size_t)t * HD + lane] = acc;                     // coalesced
        float t0 = acc * as_, t1 = acc * ad_;
        if (H == 8) {
            #pragma unroll
            for (int m = 1; m < 8; m <<= 1) {
                t0 += __shfl_xor(t0, m, 64);
                t1 += __shfl_xor(t1, m, 64);
            }
            if ((lane & 7) == 0) {
                es[t * 8 + (lane >> 3)] = t0;
                ed[t * 8 + (lane >> 3)] = t1;
            }
        } else {
            #pragma unroll
            for (int m = 1; m < 64; m <<= 1) {
                t0 += __shfl_xor(t0, m, 64);
                t1 += __shfl_xor(t1, m, 64);
            }
            if (lane == 0) { es[t] = t0; ed[t] = t1; }
        }
    }
}

// layer 0: proj fused in. h row computed per-lane, broadcast via LDS row write.
__global__ __launch_bounds__(256, 4)
void fused0_kernel(const float* __restrict__ x, const float* __restrict__ pw,
                   const float* __restrict__ pb, const float* __restrict__ w,
                   const float* __restrict__ asrc, const float* __restrict__ adst,
                   float* __restrict__ xe, float* __restrict__ es, float* __restrict__ ed) {
    __shared__ float tile[GT * HD];
    __shared__ float xt[S * GT];
    int base = blockIdx.x * GT;
    for (int i = threadIdx.x; i < S * GT; i += 256) {
        int s = i >> 6, nl = i & 63;
        int t = base + nl, bb = t / N, n = t - bb * N;
        xt[i] = x[(bb * S + s) * N + n];          // coalesced per s-segment
    }
    int lane = threadIdx.x & 63;
    float wres[HD];
    #pragma unroll
    for (int c = 0; c < HD; ++c) wres[c] = w[c * HD + lane];
    float pwres[S];
    #pragma unroll
    for (int s = 0; s < S; ++s) pwres[s] = pw[s * HD + lane];
    float pbv = pb[lane];
    float as_ = asrc[lane], ad_ = adst[lane];
    __syncthreads();
    int wvid = threadIdx.x >> 6;
    // phase A: this wave's 16 h-rows (lane = channel), written to tile
    for (int j = wvid * 16; j < wvid * 16 + 16; ++j) {
        float hl = pbv;
        #pragma unroll
        for (int s = 0; s < S; ++s)
            hl = fmaf(xt[s * GT + j], pwres[s], hl);         // broadcast read
        tile[j * HD + lane] = hl;                            // own wave's row
    }
    // phase B: gemm + attn (reads only this wave's rows -> no barrier needed)
    for (int j = wvid * 16; j < wvid * 16 + 16; ++j) {
        int t = base + j;
        float acc = 0.f;
        #pragma unroll
        for (int cq = 0; cq < 16; ++cq) {
            float4 r = ((const float4*)tile)[j * 16 + cq];
            acc = fmaf(r.x, wres[4 * cq + 0], acc);
            acc = fmaf(r.y, wres[4 * cq + 1], acc);
            acc = fmaf(r.z, wres[4 * cq + 2], acc);
            acc = fmaf(r.w, wres[4 * cq + 3], acc);
        }
        xe[(size_t)t * HD + lane] = acc;
        float t0 = acc * as_, t1 = acc * ad_;
        #pragma unroll
        for (int m = 1; m < 8; m <<= 1) {
            t0 += __shfl_xor(t0, m, 64);
            t1 += __shfl_xor(t1, m, 64);
        }
        if ((lane & 7) == 0) {
            es[t * 8 + (lane >> 3)] = t0;
            ed[t * 8 + (lane >> 3)] = t1;
        }
    }
}

// ------- fused aggregation (R13 proven form): one wave per (batch,node) ------
// 4 groups x 16 lanes; group owns an edge, lane owns 4 channels (float4).
template<int H, bool DO_ELU>
__global__ __launch_bounds__(256, 8)
void agg_kernel(const float* __restrict__ xe, const float* __restrict__ es,
                const float* __restrict__ ed, const int* __restrict__ cnt,
                const int* __restrict__ perm, const float* __restrict__ bias,
                float* __restrict__ hout) {
    int g = blockIdx.x;                       // 20000 blocks, multiple of 8
    int bb   = (g & 7) >> 1;                  // batch from XCD pair
    int idx  = (g >> 3) * 2 + (g & 1);        // 0..4999 within batch
    int node = idx * 4 + (threadIdx.x >> 6);  // < 20000
    int lane  = threadIdx.x & 63;
    int group = lane >> 4;
    int c4    = lane & 15;
    int deg = cnt[node];
    int baseE = node * CAP;
    int h = (H == 8) ? (c4 >> 1) : 0;        // channels 4*c4..+3 lie in one head
    const float*  es_b = es + bb * (N * H);
    const float4* xe4  = (const float4*)(xe + bb * (N * HD));
    float edv = ed[(bb * N + node) * H + h];
    float4 acc = {0.f, 0.f, 0.f, 0.f};
    float ssum = 0.f;
    #pragma unroll 4
    for (int jb = 0; jb < deg; jb += 4) {
        int j = jb + group;
        bool valid = (j < deg);
        int src = perm[baseE + (valid ? j : 0)];     // slot 0 always exists
        float e = es_b[src * H + h] + edv;
        e = fmaxf(e, 0.2f * e);                      // leaky_relu(0.2)
        float p = valid ? __expf(e) : 0.f;
        ssum += p;
        float4 xv = xe4[src * 16 + c4];              // 256B/group gather
        acc.x = fmaf(p, xv.x, acc.x);
        acc.y = fmaf(p, xv.y, acc.y);
        acc.z = fmaf(p, xv.z, acc.z);
        acc.w = fmaf(p, xv.w, acc.w);
    }
    #pragma unroll
    for (int m = 16; m < 64; m <<= 1) {
        acc.x += __shfl_xor(acc.x, m, 64);
        acc.y += __shfl_xor(acc.y, m, 64);
        acc.z += __shfl_xor(acc.z, m, 64);
        acc.w += __shfl_xor(acc.w, m, 64);
        ssum  += __shfl_xor(ssum,  m, 64);
    }
    if (lane < 16) {
        float inv = 1.f / ssum;
        const float4* b4 = (const float4*)bias;
        float4 bv = b4[c4];
        float4 r;
        r.x = acc.x * inv + bv.x;
        r.y = acc.y * inv + bv.y;
        r.z = acc.z * inv + bv.z;
        r.w = acc.w * inv + bv.w;
        if (DO_ELU) {
            r.x = (r.x > 0.f) ? r.x : expm1f(r.x);
            r.y = (r.y > 0.f) ? r.y : expm1f(r.y);
            r.z = (r.z > 0.f) ? r.z : expm1f(r.z);
            r.w = (r.w > 0.f) ? r.w : expm1f(r.w);
        }
        ((float4*)hout)[(bb * N + node) * 16 + c4] = r;
    }
}

// ======== conv v7.1 (R15-proven, 67us): 1-wave blocks, rows via s_load ======
constexpr int CVN = 16;                 // nodes per (1-wave) block
__global__ __launch_bounds__(64, 2)
void conv_out_kernel(const float* __restrict__ h, const float* __restrict__ cwD,
                     const float* __restrict__ cb, const float* __restrict__ ow,
                     const float* __restrict__ ob, float* __restrict__ out) {
    __shared__ float part[CVN * HD];    // 4KB, wave-private
    int bb = blockIdx.y;
    int base = blockIdx.x * CVN;        // N = 1250*16 exact
    int lane = threadIdx.x;             // = output channel o
    float cbv = cb[lane];
    float ow0 = ow[lane * 3 + 0], ow1 = ow[lane * 3 + 1], ow2 = ow[lane * 3 + 2];
    float ob0 = ob[0], ob1 = ob[1], ob2 = ob[2];
    #pragma unroll
    for (int j = 0; j < CVN; ++j) part[j * HD + lane] = cbv;
    #pragma unroll 1
    for (int dt = 0; dt < 3; ++dt) {
        float wres[HD];                 // cwD[dt][c][lane], coalesced VMEM
        #pragma unroll
        for (int c = 0; c < HD; ++c) wres[c] = cwD[dt * (HD * HD) + c * HD + lane];
        #pragma unroll 2
        for (int j = 0; j < CVN; ++j) {
            int m = base + j + dt - 1;
            if (m >= 0 && m < N) {      // uniform branch (s_cbranch)
                const float* hp = h + ((size_t)bb * N + m) * HD;   // uniform -> s_load
                float a = 0.f;
                #pragma unroll
                for (int c = 0; c < HD; ++c)
                    a = fmaf(hp[c], wres[c], a);    // v_fma with SGPR operand
                part[j * HD + lane] += a;           // wave-local LDS RMW
            }
        }
    }
    // epilogue: relu + 64->3 via butterfly
    #pragma unroll 1
    for (int j = 0; j < CVN; ++j) {
        float v = fmaxf(part[j * HD + lane], 0.f);
        float t0 = v * ow0, t1 = v * ow1, t2 = v * ow2;
        #pragma unroll
        for (int m = 1; m < 64; m <<= 1) {
            t0 += __shfl_xor(t0, m, 64);
            t1 += __shfl_xor(t1, m, 64);
            t2 += __shfl_xor(t2, m, 64);
        }
        int n = base + j;               // always < N (1250*16 = 20000)
        if (lane < 3) {
            float r = (lane == 0) ? t0 + ob0 : (lane == 1) ? t1 + ob1 : t2 + ob2;
            out[(size_t)bb * 3 * N + lane * N + n] = r;
        }
    }
}

extern "C" void kernel_launch(void* const* d_in, const int* in_sizes, int n_in,
                              void* d_out, int out_size, void* d_ws, size_t ws_size,
                              hipStream_t stream) {
    const float* x      = (const float*)d_in[0];
    const int*   ei     = (const int*)  d_in[1];
    const float* proj_w = (const float*)d_in[2];
    const float* proj_b = (const float*)d_in[3];
    const float* g_w [3] = {(const float*)d_in[4], (const float*)d_in[8],  (const float*)d_in[12]};
    const float* g_as[3] = {(const float*)d_in[5], (const float*)d_in[9],  (const float*)d_in[13]};
    const float* g_ad[3] = {(const float*)d_in[6], (const float*)d_in[10], (const float*)d_in[14]};
    const float* g_b [3] = {(const float*)d_in[7], (const float*)d_in[11], (const float*)d_in[15]};
    const float* conv_w = (const float*)d_in[16];
    const float* conv_b = (const float*)d_in[17];
    const float* out_w  = (const float*)d_in[18];
    const float* out_b  = (const float*)d_in[19];
    float* out = (float*)d_out;

    // workspace layout (fp32 elements)
    float* bufA = (float*)d_ws;                      // BN*HD
    float* bufX = bufA + (size_t)BN * HD;            // BN*HD
    float* es   = bufX + (size_t)BN * HD;            // BN*8 (max H)
    float* ed   = es   + (size_t)BN * 8;             // BN*8
    int* cnt  = (int*)(ed + (size_t)BN * 8);         // N
    int* perm = cnt + N;                             // N*CAP
    float* cwD = (float*)(perm + (size_t)N * CAP);   // 3*64*64

    const int TB = 256;
    const int gE = (EL + TB - 1) / TB;

    // CSR build: memset + single scatter (padded buckets, no scan)
    hipMemsetAsync(cnt, 0, N * sizeof(int), stream);
    scatter_kernel<<<gE, TB, 0, stream>>>(ei, cnt, perm);

    // conv weight transpose to [dt][c][o]
    tw_kernel<<<(HD * HD * 3 + TB - 1) / TB, TB, 0, stream>>>(conv_w, cwD);

    // layer 0: proj + gemm + attn fused (reads x directly)
    fused0_kernel<<<BN / GT, TB, 0, stream>>>(x, proj_w, proj_b, g_w[0], g_as[0], g_ad[0],
                                              bufX, es, ed);
    agg_kernel<8, true><<<BN / 4, TB, 0, stream>>>(bufX, es, ed, cnt, perm, g_b[0], bufA);

    // layer 1 (H=8) + ELU
    gemm_attn_kernel<8><<<BN / GT, TB, 0, stream>>>(bufA, g_w[1], g_as[1], g_ad[1], bufX, es, ed);
    agg_kernel<8, true><<<BN / 4, TB, 0, stream>>>(bufX, es, ed, cnt, perm, g_b[1], bufA);

    // layer 2 (H=1), no ELU
    gemm_attn_kernel<1><<<BN / GT, TB, 0, stream>>>(bufA, g_w[2], g_as[2], g_ad[2], bufX, es, ed);
    agg_kernel<1, false><<<BN / 4, TB, 0, stream>>>(bufX, es, ed, cnt, perm, g_b[2], bufA);

    // conv1d(k=3) + relu + final projection, writes [B,3,N]
    conv_out_kernel<<<dim3(N / CVN, B), 64, 0, stream>>>(bufA, cwD, conv_b, out_w, out_b, out);
}